// Round 7
// baseline (269.102 us; speedup 1.0000x reference)
//
#include <hip/hip_runtime.h>
#include <hip/hip_bf16.h>
#include <math.h>

#define LDIM 4096
#define NROWS 8192
#define NOUT 512

static const float SQRT_HALF_F = 0.70710678118654752440f;

typedef __attribute__((ext_vector_type(8))) short short8;
typedef __attribute__((ext_vector_type(4))) float f32x4;
typedef __attribute__((ext_vector_type(8))) unsigned short u16x8;
typedef __attribute__((ext_vector_type(4))) unsigned short u16x4;
typedef __attribute__((ext_vector_type(2))) unsigned short u16x2;

// ws layout
#define AM_OFF   0ull                         // bf16 masked A: 8192*4096*2 = 67108864
#define WT_OFF   67108864ull                  // bf16 Wt (N x K): 512*4096*2 = 4194304
#define PART_OFF (WT_OFF + 4194304ull)        // double[8192*2] partials
#define THR_OFF  (PART_OFF + 131072ull)       // float[1]

__device__ inline unsigned short f2bf(float f) {
  union { float f; unsigned u; } v; v.f = f;
  unsigned r = (v.u + 0x7fffu + ((v.u >> 16) & 1u)) >> 16;
  return (unsigned short)r;
}

__device__ inline unsigned short mcvt(float f, float thr) {
  return f2bf((fabsf(f) > thr) ? f : 0.0f);
}

__device__ inline void async16(void* l, const void* g) {
  __builtin_amdgcn_global_load_lds((const __attribute__((address_space(1))) void*)g,
                                   (__attribute__((address_space(3))) void*)l, 16, 0, 0);
}

// ---------------- Kernel 1: Haar stats (blocks 0..8191) + W convert (tail) ----
__global__ __launch_bounds__(256) void haar1_kernel(const float* __restrict__ x,
                                                    double* __restrict__ partials,
                                                    const float* __restrict__ W,
                                                    unsigned short* __restrict__ Wt) {
  if (blockIdx.x >= NROWS) {
    // ---- fused wcvt: W (K x N fp32) -> Wt (N x K bf16) ----
    __shared__ float tile[32][33];
    const int wb = blockIdx.x - NROWS;
    const int bx = wb & 15;        // n tile (16)
    const int by = wb >> 4;        // k tile (128)
    const int tx = threadIdx.x & 31, ty = threadIdx.x >> 5;
#pragma unroll
    for (int j = 0; j < 4; ++j)
      tile[ty + j * 8][tx] = W[(size_t)(by * 32 + ty + j * 8) * NOUT + bx * 32 + tx];
    __syncthreads();
#pragma unroll
    for (int j = 0; j < 4; ++j)
      Wt[(size_t)(bx * 32 + ty + j * 8) * LDIM + by * 32 + tx] = f2bf(tile[tx][ty + j * 8]);
    return;
  }

  __shared__ double red[8];
  const int row = blockIdx.x;
  const int t = threadIdx.x;
  const float S = SQRT_HALF_F;

  const float4* xr = (const float4*)(x + (size_t)row * LDIM) + 4 * t;
  float v[16];
#pragma unroll
  for (int k = 0; k < 4; ++k) {
    float4 q = xr[k];
    v[4 * k] = q.x; v[4 * k + 1] = q.y; v[4 * k + 2] = q.z; v[4 * k + 3] = q.w;
  }

  double sa = 0.0, sq = 0.0;
  float a1[8], a2[4], a3[2], a4;
#pragma unroll
  for (int j = 0; j < 8; ++j) {
    float d = (v[2 * j] - v[2 * j + 1]) * S;
    a1[j] = (v[2 * j] + v[2 * j + 1]) * S;
    sa += (double)fabsf(d); sq += (double)d * (double)d;
  }
#pragma unroll
  for (int j = 0; j < 4; ++j) {
    float d = (a1[2 * j] - a1[2 * j + 1]) * S;
    a2[j] = (a1[2 * j] + a1[2 * j + 1]) * S;
    sa += (double)fabsf(d); sq += (double)d * (double)d;
  }
#pragma unroll
  for (int j = 0; j < 2; ++j) {
    float d = (a2[2 * j] - a2[2 * j + 1]) * S;
    a3[j] = (a2[2 * j] + a2[2 * j + 1]) * S;
    sa += (double)fabsf(d); sq += (double)d * (double)d;
  }
  {
    float d = (a3[0] - a3[1]) * S;
    a4 = (a3[0] + a3[1]) * S;
    sa += (double)fabsf(d); sq += (double)d * (double)d;
  }
  {
    float other = __shfl_xor(a4, 1, 64);
    if ((t & 1) == 0) {
      float d = (a4 - other) * S, ap = (a4 + other) * S;
      sa += (double)fabsf(d) + (double)fabsf(ap);
      sq += (double)d * (double)d + (double)ap * (double)ap;
    }
  }

  const int lane = t & 63, wid = t >> 6;
#pragma unroll
  for (int off = 32; off > 0; off >>= 1) {
    sa += __shfl_down(sa, off, 64);
    sq += __shfl_down(sq, off, 64);
  }
  if (lane == 0) { red[wid] = sa; red[4 + wid] = sq; }
  __syncthreads();
  if (t == 0) {
    partials[2 * (size_t)row + 0] = red[0] + red[1] + red[2] + red[3];
    partials[2 * (size_t)row + 1] = red[4] + red[5] + red[6] + red[7];
  }
}

// ---------------- Kernel 2: reduce partials -> threshold ----------------
__global__ __launch_bounds__(1024) void thr_kernel(const double* __restrict__ partials,
                                                   float* __restrict__ thr) {
  __shared__ double red[32];
  const int tid = threadIdx.x;
  double sa = 0.0, sq = 0.0;
#pragma unroll
  for (int k = 0; k < NROWS / 1024; ++k) {
    int i = tid + k * 1024;
    sa += partials[2 * i + 0];
    sq += partials[2 * i + 1];
  }
  const int lane = tid & 63, wid = tid >> 6;
#pragma unroll
  for (int off = 32; off > 0; off >>= 1) {
    sa += __shfl_down(sa, off, 64);
    sq += __shfl_down(sq, off, 64);
  }
  if (lane == 0) { red[wid] = sa; red[16 + wid] = sq; }
  __syncthreads();
  if (tid == 0) {
    double s = 0.0, q = 0.0;
#pragma unroll
    for (int i = 0; i < 16; ++i) { s += red[i]; q += red[16 + i]; }
    const double n = (double)NROWS * (double)LDIM;
    double mean = s / n;
    double var = (q - s * s / n) / (n - 1.0);
    *thr = (float)(mean + sqrt(var));
  }
}

// ---------------- Kernel 3: Haar recompute + mask + bf16 write ----------------
__global__ __launch_bounds__(256) void haar2_kernel(const float* __restrict__ x,
                                                    const float* __restrict__ thrp,
                                                    unsigned short* __restrict__ Am) {
  const float thr = *thrp;
  const int row = blockIdx.x;
  const int t = threadIdx.x;
  const float S = SQRT_HALF_F;

  const float4* xr = (const float4*)(x + (size_t)row * LDIM) + 4 * t;
  float v[16];
#pragma unroll
  for (int k = 0; k < 4; ++k) {
    float4 q = xr[k];
    v[4 * k] = q.x; v[4 * k + 1] = q.y; v[4 * k + 2] = q.z; v[4 * k + 3] = q.w;
  }

  unsigned short* orow = Am + (size_t)row * LDIM;
  float a1[8], a2[4], a3[2], a4;

  u16x8 d1;
#pragma unroll
  for (int j = 0; j < 8; ++j) {
    float d = (v[2 * j] - v[2 * j + 1]) * S;
    a1[j] = (v[2 * j] + v[2 * j + 1]) * S;
    d1[j] = mcvt(d, thr);
  }
  *(u16x8*)(orow + 2048 + 8 * t) = d1;

  u16x4 d2;
#pragma unroll
  for (int j = 0; j < 4; ++j) {
    float d = (a1[2 * j] - a1[2 * j + 1]) * S;
    a2[j] = (a1[2 * j] + a1[2 * j + 1]) * S;
    d2[j] = mcvt(d, thr);
  }
  *(u16x4*)(orow + 1024 + 4 * t) = d2;

  u16x2 d3;
#pragma unroll
  for (int j = 0; j < 2; ++j) {
    float d = (a2[2 * j] - a2[2 * j + 1]) * S;
    a3[j] = (a2[2 * j] + a2[2 * j + 1]) * S;
    d3[j] = mcvt(d, thr);
  }
  *(u16x2*)(orow + 512 + 2 * t) = d3;

  {
    float d = (a3[0] - a3[1]) * S;
    a4 = (a3[0] + a3[1]) * S;
    orow[256 + t] = mcvt(d, thr);
  }
  {
    float other = __shfl_xor(a4, 1, 64);
    if ((t & 1) == 0) {
      float d = (a4 - other) * S, ap = (a4 + other) * S;
      orow[128 + t / 2] = mcvt(d, thr);
      orow[t / 2] = mcvt(ap, thr);
    }
  }
}

// ---------------- Kernel 4: bf16 MFMA GEMM + ReLU ----------------
// Tile 64m x 64n, BK=128, 256 threads (4 waves, wave tile 32x32, 16 MFMA/iter),
// grid 1024 = 4 blocks/CU (__launch_bounds__(256,4), 32 KB LDS/block).
// LDS layout (set by DMA): chunk c (16 B) of row r lives at
//   (r>>3)*1024 + (c>=8 ? 512 : 0) + (r&7)*64 + ((c&7)^(r&7))*8
// i.e. [group][k-half][row-in-group][xor-swizzled chunk]. ROUND-6 BUG: reader
// used row*128 + ((c&8)|((c^row)&7))*8 which mismatches this layout for
// groups>0 -> absmax 5.69. Fixed below. Per-quad bank spread: (c^r)&7 cycles
// all 8 positions across in-group rows -> <=2-way aliasing (free, m136).
__global__ __launch_bounds__(256, 4) void gemm_kernel(const unsigned short* __restrict__ Am,
                                                      const unsigned short* __restrict__ Wt,
                                                      float* __restrict__ out) {
  __shared__ __align__(16) unsigned short As[64 * 128];  // 16 KB
  __shared__ __align__(16) unsigned short Bs[64 * 128];  // 16 KB

  const int tid = threadIdx.x;
  const int lane = tid & 63, w = tid >> 6;      // 4 waves
  const int quad = lane >> 4, l15 = lane & 15;
  const int wm = w >> 1, wn = w & 1;            // 2 x 2 wave grid

  const int id = blockIdx.x;
  const int xcd = id & 7, slot = id >> 3;       // slot 0..127
  const int nblk = slot & 7;                    // 8 n-blocks
  const int mblk = (slot >> 3) * 8 + xcd;       // 128 m-strips
  const int n0 = nblk * 64, m0 = mblk * 64;

  f32x4 acc[2][2] = {};

  // DMA source: lane (rl, p) reads chunk cg = p^rl of row rl -> lands at
  // in-group position p (lane-ordered), giving the layout documented above.
  const int rl = lane >> 3;            // row within 8-row group
  const int cg = (lane & 7) ^ rl;      // swizzled source chunk
  const unsigned short* AgBase = Am + (size_t)(m0 + rl) * LDIM + cg * 8;
  const unsigned short* BgBase = Wt + (size_t)(n0 + rl) * LDIM + cg * 8;

  for (int k0 = 0; k0 < LDIM; k0 += 128) {
#pragma unroll
    for (int j = 0; j < 2; ++j) {
      const int g = w * 2 + j;
      const size_t gro = (size_t)(g * 8) * LDIM + k0;
      async16(&As[g * 1024], AgBase + gro);                  // k-chunks 0..7
      async16(&As[g * 1024 + 512], AgBase + gro + 64);       // k-chunks 8..15
      async16(&Bs[g * 1024], BgBase + gro);
      async16(&Bs[g * 1024 + 512], BgBase + gro + 64);
    }
    __syncthreads();

    short8 af[2][4], bf[2][4];
#pragma unroll
    for (int mi = 0; mi < 2; ++mi) {
      const int row = wm * 32 + mi * 16 + l15;
      const int rg = row >> 3, ro = row & 7;
#pragma unroll
      for (int ks = 0; ks < 4; ++ks) {
        const int c = ks * 4 + quad;
        af[mi][ks] = *(const short8*)&As[rg * 1024 + (c & 8) * 64 + ro * 64 + ((c ^ ro) & 7) * 8];
      }
    }
#pragma unroll
    for (int ni = 0; ni < 2; ++ni) {
      const int row = wn * 32 + ni * 16 + l15;
      const int rg = row >> 3, ro = row & 7;
#pragma unroll
      for (int ks = 0; ks < 4; ++ks) {
        const int c = ks * 4 + quad;
        bf[ni][ks] = *(const short8*)&Bs[rg * 1024 + (c & 8) * 64 + ro * 64 + ((c ^ ro) & 7) * 8];
      }
    }
#pragma unroll
    for (int ks = 0; ks < 4; ++ks)
#pragma unroll
      for (int mi = 0; mi < 2; ++mi)
#pragma unroll
        for (int ni = 0; ni < 2; ++ni)
          acc[mi][ni] = __builtin_amdgcn_mfma_f32_16x16x32_bf16(af[mi][ks], bf[ni][ks],
                                                                acc[mi][ni], 0, 0, 0);
    __syncthreads();
  }

  // C/D layout: col = lane&15, row = quad*4 + reg (verified rounds 1-5)
#pragma unroll
  for (int mi = 0; mi < 2; ++mi) {
#pragma unroll
    for (int ni = 0; ni < 2; ++ni) {
      const int r0 = m0 + wm * 32 + mi * 16 + quad * 4;
      const int c = n0 + wn * 32 + ni * 16 + l15;
#pragma unroll
      for (int r = 0; r < 4; ++r)
        out[(size_t)(r0 + r) * NOUT + c] = fmaxf(acc[mi][ni][r], 0.0f);
    }
  }
}

extern "C" void kernel_launch(void* const* d_in, const int* in_sizes, int n_in,
                              void* d_out, int out_size, void* d_ws, size_t ws_size,
                              hipStream_t stream) {
  const float* x = (const float*)d_in[0];
  const float* W = (const float*)d_in[1];
  float* out = (float*)d_out;

  char* ws = (char*)d_ws;
  unsigned short* Am = (unsigned short*)(ws + AM_OFF);
  unsigned short* Wt = (unsigned short*)(ws + WT_OFF);
  double* partials = (double*)(ws + PART_OFF);
  float* thr = (float*)(ws + THR_OFF);

  haar1_kernel<<<NROWS + 2048, 256, 0, stream>>>(x, partials, W, Wt);
  thr_kernel<<<1, 1024, 0, stream>>>(partials, thr);
  haar2_kernel<<<NROWS, 256, 0, stream>>>(x, thr, Am);
  gemm_kernel<<<1024, 256, 0, stream>>>(Am, Wt, out);
}